// Round 11
// baseline (333.745 us; speedup 1.0000x reference)
//
#include <hip/hip_runtime.h>

// Problem constants (fixed by the reference)
#define Bn 2
#define Nn 256
#define Mn 512
#define Cn 256
#define Hn 8
#define MT 64             // m-tile size (8 tiles, double-buffered emb)
#define SCALE_ 0.17677669529663687f   // Dh^-0.5, Dh=32
#define INV2PI 0.15915494309189535f

typedef short bf16x8 __attribute__((ext_vector_type(8)));
typedef short bf16x4 __attribute__((ext_vector_type(4)));
typedef float f32x4 __attribute__((ext_vector_type(4)));

static __device__ __forceinline__ float b2f(short s) {
    unsigned u = ((unsigned)(unsigned short)s) << 16;
    return __builtin_bit_cast(float, u);
}
static __device__ __forceinline__ short f2b(float f) {   // RNE f32->bf16
    unsigned u = __builtin_bit_cast(unsigned, f);
    u += 0x7fffu + ((u >> 16) & 1u);
    return (short)(u >> 16);
}
static __device__ __forceinline__ void async16(const void* g, void* l) {
    __builtin_amdgcn_global_load_lds(
        (const __attribute__((address_space(1))) unsigned int*)g,
        (__attribute__((address_space(3))) unsigned int*)l, 16, 0, 0);
}

// ---- prep2: W1/W2 convert (vectorized) + k'/v' projections ----
// bid 0..63: convert (8 elems/thread). 64..319: k' (swizzled [b][m][c] bf16).
// 320..575: v' (plain [b][m][c] bf16).
__global__ __launch_bounds__(256) void prep2(
        const float* __restrict__ key, const float* __restrict__ Wk,
        const float* __restrict__ Wv, const float* __restrict__ bv,
        const float* __restrict__ W1, const float* __restrict__ W2,
        short* __restrict__ W1b, short* __restrict__ W2b,
        short* __restrict__ kpb, short* __restrict__ vpb) {
    __shared__ float arow[32][Cn];
    const int bid = blockIdx.x;
    const int t = threadIdx.x;
    if (bid < 64) {                        // convert W1/W2 to bf16, 8/thread
        const int half = bid >> 5;
        const int off = (bid & 31) * 2048 + t * 8;
        const float* src = half ? W2 : W1;
        short* dst = half ? W2b : W1b;
        const float4 a = *(const float4*)(src + off);
        const float4 c = *(const float4*)(src + off + 4);
        bf16x8 p;
        p[0] = f2b(a.x); p[1] = f2b(a.y); p[2] = f2b(a.z); p[3] = f2b(a.w);
        p[4] = f2b(c.x); p[5] = f2b(c.y); p[6] = f2b(c.z); p[7] = f2b(c.w);
        *(bf16x8*)(dst + off) = p;
        return;
    }
    const int isv = bid >= 320;
    const int id = bid - (isv ? 320 : 64);
    const int r0 = (id >> 3) * 32, c0 = (id & 7) * 32;
    const float* W = isv ? Wv : Wk;
    #pragma unroll
    for (int i = 0; i < 32; ++i) arow[i][t] = key[(size_t)(r0 + i) * Cn + t];
    __syncthreads();
    const int col = c0 + (t & 31);
    const int rs = t >> 5;                 // 8 slots x 4 rows
    float a4[4] = {0.f, 0.f, 0.f, 0.f};
    const float* wr = W + (size_t)col * Cn;
    for (int k = 0; k < Cn; k += 4) {
        const float4 wv = *(const float4*)(wr + k);
        #pragma unroll
        for (int i = 0; i < 4; ++i) {
            const int r = rs * 4 + i;
            a4[i] += arow[r][k] * wv.x + arow[r][k+1] * wv.y
                   + arow[r][k+2] * wv.z + arow[r][k+3] * wv.w;
        }
    }
    if (!isv) {                            // k': swizzled rows (async16+ds_read pair)
        const int bk = r0 >> 9, mm0 = (r0 & 511) + rs * 4;
        char* base = (char*)kpb + (size_t)bk * Mn * Cn * 2;
        #pragma unroll
        for (int i = 0; i < 4; ++i) {
            const int m = mm0 + i;
            *(short*)(base + m * 512 + ((col * 2) ^ ((m & 7) << 4))) = f2b(a4[i]);
        }
    } else {                               // v': plain [m][c]
        const float bvv = bv[col];
        #pragma unroll
        for (int i = 0; i < 4; ++i)
            vpb[(size_t)(r0 + rs * 4 + i) * Cn + col] = f2b(a4[i] + bvv);
    }
}

// ---- fused: q'-proj + MLP + gated scores + softmax + PV + out-proj ----
// 512 threads = 8 waves; wave w owns channel slice [w*32,w*32+32) == head w.
// MT=64, embS double-buffered: emb[t+1] (pure VALU) is emitted inside the
// GEMM1[t] region so the scheduler hides it under MFMA issue.
// LDS ~107 KB -> 1 block/CU; 128 arch VGPRs (R10-proven spill-free pattern).
__global__ __launch_bounds__(512, 1) void fused_attn(
        const float* __restrict__ query, const float* __restrict__ Wq,
        const float* __restrict__ bq, const short* __restrict__ kpb,
        const short* __restrict__ vpb, const float* __restrict__ qpos,
        const short* __restrict__ W1b, const short* __restrict__ W2b,
        const float* __restrict__ b1, const float* __restrict__ b2,
        const float* __restrict__ freqs, const float* __restrict__ Wo,
        const float* __restrict__ bo, float* __restrict__ xout) {
    __shared__ __align__(16) char embS[2][MT * 512]; // 2x32 KB emb/S dbuf, swizzled
    __shared__ __align__(16) char kS[MT * 512];      // 32 KB K tile [m][c] swz
    __shared__ float tposS[Mn];                      // 2 KB qpos row
    __shared__ float fbuf[128];                      // freqs / 2pi
    __shared__ float qbuf[Cn];                       // q' row, pre-scaled
    __shared__ float b2buf[Cn];
    __shared__ float scb2[Hn * MT];                  // scores -> weights -> x
    __shared__ float pacc[512];
    __shared__ float corrS[Hn], lS[Hn];

    const int t = threadIdx.x;
    const int lane = t & 63;
    const int w = t >> 6;                 // wave id = head id = col-slice id
    const int lr = lane & 15, lg = lane >> 4;

    // XCD-chunked bijective swizzle: 512 blocks = 8 XCDs x 64 contiguous
    const int qrow = ((blockIdx.x & 7) << 6) | (blockIdx.x >> 3);
    const int b = qrow >> 8;              // batch

    const int cA = w * 32 + lr, cB = cA + 16;
    const short* w1p0 = W1b + (size_t)cA * Cn + lg * 8;
    const short* w1p1 = W1b + (size_t)cB * Cn + lg * 8;
    const short* w2p0 = W2b + (size_t)cA * Cn + lg * 8;
    const short* w2p1 = W2b + (size_t)cB * Cn + lg * 8;
    const float b1v0 = b1[cA], b1v1 = b1[cB];

    // emb generator: thread = row m = t>>3, freq group fg = t&7 (16 freqs)
    auto emb_compute = [&](int m0w, char* buf) {
        const int m = t >> 3, fg = t & 7;
        const float tv = tposS[(m0w + m) & (Mn - 1)];
        char* rowp = buf + m * 512;
        const int sw = (m & 7) << 4;
        #pragma unroll
        for (int j8 = 0; j8 < 2; ++j8) {
            bf16x8 pc, ps;
            #pragma unroll
            for (int e = 0; e < 8; ++e) {
                const float xr = tv * fbuf[fg * 16 + j8 * 8 + e];
                pc[e] = f2b(__builtin_amdgcn_cosf(xr));
                ps[e] = f2b(__builtin_amdgcn_sinf(xr));
            }
            *(bf16x8*)(rowp + ((fg * 32 + j8 * 16) ^ sw)) = pc;        // cos
            *(bf16x8*)(rowp + ((256 + fg * 32 + j8 * 16) ^ sw)) = ps;  // sin
        }
    };
    auto stage_k = [&](int m0w) {
        const size_t tbase = ((size_t)(b * Mn + (m0w & (Mn - 1)))) * Cn * 2;
        #pragma unroll
        for (int i = 0; i < 4; ++i) {
            const int seg = (i * 8 + w) * 1024;
            async16((const char*)kpb + tbase + seg + lane * 16, kS + seg);
        }
    };

    // ---- prologue: constants + q' GEMV + emb[0] + K[0] ----
    tposS[t] = qpos[(size_t)qrow * Mn + t];
    if (t < 128) fbuf[t] = freqs[t] * INV2PI;
    if (t < 256) {
        b2buf[t] = b2[t];
        scb2[t] = query[(size_t)qrow * Cn + t];   // temp stage of query row
    }
    __syncthreads();
    {
        const int c = t & 255, half = t >> 8;
        const float* wr = Wq + (size_t)c * Cn + half * 128;
        const float* xb = scb2 + half * 128;
        float s = 0.f;
        for (int k = 0; k < 128; k += 4) {
            const float4 wv = *(const float4*)(wr + k);
            s += xb[k] * wv.x + xb[k+1] * wv.y + xb[k+2] * wv.z + xb[k+3] * wv.w;
        }
        pacc[t] = s;
    }
    __syncthreads();
    if (t < 256) qbuf[t] = (pacc[t] + pacc[t + 256] + bq[t]) * SCALE_;
    emb_compute(0, embS[0]);
    stage_k(0);

    float m_run = -1e30f, l_run = 0.f;
    float xacc = 0.f;                     // t<256: output channel t
    bf16x8 wreg[16];                      // time-shared W fragment buffer

    for (int tix = 0; tix < Mn / MT; ++tix) {
        const int m0 = tix * MT;
        char* bufc = embS[tix & 1];
        char* bufn = embS[(tix + 1) & 1];

        __syncthreads();                  // (A) emb[t]+K[t] visible (vmcnt drained)
        // deferred accumulate of previous tile's PV partials
        if (tix > 0 && t < 256) xacc = xacc * corrS[t >> 5] + pacc[t] + pacc[t + 256];

        // phase 2: GEMM1 hidden = emb @ W1^T  + pipelined emb[t+1] (hidden under MFMA)
        {
            int woff = 0;
            asm volatile("" : "+v"(woff));
            #pragma unroll
            for (int kk = 0; kk < 8; ++kk) {
                wreg[kk] = *(const bf16x8*)(w1p0 + woff + kk * 32);
                wreg[8 + kk] = *(const bf16x8*)(w1p1 + woff + kk * 32);
            }
        }
        f32x4 acc[4][2];
        #pragma unroll
        for (int pb = 0; pb < 4; ++pb) {
            acc[pb][0] = (f32x4){0.f, 0.f, 0.f, 0.f};
            acc[pb][1] = (f32x4){0.f, 0.f, 0.f, 0.f};
        }
        #pragma unroll
        for (int pb = 0; pb < 4; ++pb) {
            const int row = pb * 16 + lr;
            const int sw = (row & 7) << 4;
            const char* rowp = bufc + row * 512;
            #pragma unroll
            for (int kk = 0; kk < 8; ++kk) {
                const bf16x8 a = *(const bf16x8*)(rowp + ((lg * 16 + kk * 64) ^ sw));
                acc[pb][0] = __builtin_amdgcn_mfma_f32_16x16x32_bf16(a, wreg[kk],     acc[pb][0], 0, 0, 0);
                acc[pb][1] = __builtin_amdgcn_mfma_f32_16x16x32_bf16(a, wreg[8 + kk], acc[pb][1], 0, 0, 0);
            }
        }
        emb_compute(m0 + MT, bufn);       // independent VALU: interleaves with MFMA
        __syncthreads();                  // (B) GEMM1 A-reads done; bufc writable

        // silu + store S into bufc (swizzled); W2 refill drains underneath
        {
            int woff = 0;
            asm volatile("" : "+v"(woff));
            #pragma unroll
            for (int kk = 0; kk < 8; ++kk) {
                wreg[kk] = *(const bf16x8*)(w2p0 + woff + kk * 32);
                wreg[8 + kk] = *(const bf16x8*)(w2p1 + woff + kk * 32);
            }
        }
        #pragma unroll
        for (int pb = 0; pb < 4; ++pb) {
            #pragma unroll
            for (int jb = 0; jb < 2; ++jb) {
                const float bv = jb ? b1v1 : b1v0;
                const int j = w * 32 + jb * 16 + lr;
                #pragma unroll
                for (int r = 0; r < 4; ++r) {
                    const int row = pb * 16 + lg * 4 + r;   // C/D: row = 4*(lane>>4)+reg
                    float hv = acc[pb][jb][r] + bv;
                    hv = hv / (1.f + __expf(-hv));
                    *(short*)(bufc + row * 512 + ((j * 2) ^ ((row & 7) << 4))) = f2b(hv);
                }
            }
        }
        __syncthreads();                  // (C) S visible

        // phase 3: SWAPPED GEMM2  D2 = W2slice @ S^T  (+b2 via acc init)
        // lane (lr,lg) reg r of acc[mb][cb]: D2[c=w*32+cb*16+lg*4+r][m=mb*16+lr]
        {
            float b2a[8];
            #pragma unroll
            for (int i = 0; i < 8; ++i)
                b2a[i] = b2buf[w * 32 + (i >> 2) * 16 + lg * 4 + (i & 3)];
            #pragma unroll
            for (int mb = 0; mb < 4; ++mb)
                #pragma unroll
                for (int cb = 0; cb < 2; ++cb)
                    #pragma unroll
                    for (int r = 0; r < 4; ++r)
                        acc[mb][cb][r] = b2a[cb * 4 + r];
        }
        #pragma unroll
        for (int mb = 0; mb < 4; ++mb) {
            const int row = mb * 16 + lr;
            const int sw = (row & 7) << 4;
            const char* rowp = bufc + row * 512;
            #pragma unroll
            for (int kk = 0; kk < 8; ++kk) {
                const bf16x8 a = *(const bf16x8*)(rowp + ((lg * 16 + kk * 64) ^ sw));
                acc[mb][0] = __builtin_amdgcn_mfma_f32_16x16x32_bf16(wreg[kk],     a, acc[mb][0], 0, 0, 0);
                acc[mb][1] = __builtin_amdgcn_mfma_f32_16x16x32_bf16(wreg[8 + kk], a, acc[mb][1], 0, 0, 0);
            }
        }

        // phase 4: s[m] = sum_c q[c]*k[m][c]*D2[c][m]; K from kS; 2-shuffle reduce
        {
            float qa[8];
            #pragma unroll
            for (int i = 0; i < 8; ++i)
                qa[i] = qbuf[w * 32 + (i >> 2) * 16 + lg * 4 + (i & 3)];
            #pragma unroll
            for (int mb = 0; mb < 4; ++mb) {
                const int m = mb * 16 + lr;
                const int sw = (m & 7) << 4;
                const char* kr = kS + m * 512;
                const int cc0 = (w * 32 + lg * 4) * 2;
                const bf16x4 k0 = *(const bf16x4*)(kr + (cc0 ^ sw));
                const bf16x4 k1 = *(const bf16x4*)(kr + ((cc0 + 32) ^ sw));
                float partial = 0.f;
                #pragma unroll
                for (int r = 0; r < 4; ++r) {
                    partial += qa[r] * b2f(k0[r]) * acc[mb][0][r]
                             + qa[4 + r] * b2f(k1[r]) * acc[mb][1][r];
                }
                partial += __shfl_xor(partial, 16);
                partial += __shfl_xor(partial, 32);
                if (lg == 0) scb2[w * MT + m] = partial;
            }
        }

        // phase 5: wave-local online softmax for head w
        {
            const float s = scb2[w * MT + lane];
            float tmax = s;
            #pragma unroll
            for (int msk = 1; msk < 64; msk <<= 1) tmax = fmaxf(tmax, __shfl_xor(tmax, msk));
            const float mnew = fmaxf(m_run, tmax);
            const float corr = __expf(m_run - mnew);
            const float e = __expf(s - mnew);
            scb2[w * MT + lane] = e;
            float ss = e;
            #pragma unroll
            for (int msk = 1; msk < 64; msk <<= 1) ss += __shfl_xor(ss, msk);
            l_run = l_run * corr + ss;
            m_run = mnew;
            if (lane == 0) corrS[w] = corr;
        }
        __syncthreads();                  // (D) weights + corrS visible; kS reads done

        stage_k(m0 + MT);                 // K[t+1] issue; drains under PV + next emb

        // phase 6: PV partials; V direct from L2 (coalesced over c).
        // thread: c = t&255, m-half = t>>8 (32 m each)
        {
            const int c = t & 255, half = t >> 8;
            const int h = c >> 5;
            const short* vrow = vpb + ((size_t)(b * Mn + m0 + half * 32)) * Cn + c;
            const float* wr2 = scb2 + h * MT + half * 32;
            float s = 0.f;
            #pragma unroll
            for (int i = 0; i < 8; ++i) {
                const float4 wa = *(const float4*)(wr2 + i * 4);
                s += wa.x * b2f(vrow[(size_t)(i * 4 + 0) * Cn])
                   + wa.y * b2f(vrow[(size_t)(i * 4 + 1) * Cn])
                   + wa.z * b2f(vrow[(size_t)(i * 4 + 2) * Cn])
                   + wa.w * b2f(vrow[(size_t)(i * 4 + 3) * Cn]);
            }
            pacc[t] = s;
        }
        // no barrier here: next iteration's (A) publishes pacc, then we accumulate
    }
    __syncthreads();                      // final pacc visible
    if (t < 256) xacc = xacc * corrS[t >> 5] + pacc[t] + pacc[t + 256];

    // epilogue: softmax norm, fused out-projection + bias + residual
    if (lane == 0) lS[w] = l_run;
    __syncthreads();
    if (t < 256) scb2[t] = xacc / lS[t >> 5];    // x vector (256 f32)
    __syncthreads();
    {
        const int j = t & 255, half = t >> 8;
        const float* wr = Wo + (size_t)j * Cn + half * 128;
        const float* xb = scb2 + half * 128;
        float s = 0.f;
        for (int k = 0; k < 128; k += 4) {
            const float4 wv = *(const float4*)(wr + k);
            s += xb[k] * wv.x + xb[k+1] * wv.y + xb[k+2] * wv.z + xb[k+3] * wv.w;
        }
        pacc[t] = s;
    }
    __syncthreads();
    if (t < 256)
        xout[(size_t)qrow * Cn + t] = pacc[t] + pacc[t + 256] + bo[t]
                                    + query[(size_t)qrow * Cn + t];
}

extern "C" void kernel_launch(void* const* d_in, const int* in_sizes, int n_in,
                              void* d_out, int out_size, void* d_ws, size_t ws_size,
                              hipStream_t stream) {
    const float* query = (const float*)d_in[0];
    const float* key   = (const float*)d_in[1];
    const float* qpos  = (const float*)d_in[2];
    const float* Wq    = (const float*)d_in[3];
    const float* bq    = (const float*)d_in[4];
    const float* Wk    = (const float*)d_in[5];
    const float* Wv    = (const float*)d_in[6];
    const float* bv    = (const float*)d_in[7];
    const float* Wo    = (const float*)d_in[8];
    const float* bo    = (const float*)d_in[9];
    const float* W1    = (const float*)d_in[10];
    const float* b1    = (const float*)d_in[11];
    const float* W2    = (const float*)d_in[12];
    const float* b2    = (const float*)d_in[13];
    const float* freqs = (const float*)d_in[14];
    float* out = (float*)d_out;

    char* ws = (char*)d_ws;
    short* kpb = (short*)(ws);                 // 512 KB  (B*M*C bf16, row-swizzled)
    short* vpb = (short*)(ws + 524288);        // 512 KB  (B*M*C bf16, plain)
    short* W1b = (short*)(ws + 1048576);       // 128 KB bf16
    short* W2b = (short*)(ws + 1179648);       // 128 KB bf16

    prep2<<<576, 256, 0, stream>>>(key, Wk, Wv, bv, W1, W2, W1b, W2b, kpb, vpb);
    fused_attn<<<Bn * Nn, 512, 0, stream>>>(query, Wq, bq, kpb, vpb, qpos,
                                            W1b, W2b, b1, b2, freqs, Wo, bo, out);
}

// Round 12
// 318.444 us; speedup vs baseline: 1.0480x; 1.0480x over previous
//
#include <hip/hip_runtime.h>

// Problem constants (fixed by the reference)
#define Bn 2
#define Nn 256
#define Mn 512
#define Cn 256
#define Hn 8
#define MT 64             // m-tile size (8 tiles)
#define SCALE_ 0.17677669529663687f   // Dh^-0.5, Dh=32
#define INV2PI 0.15915494309189535f

typedef short bf16x8 __attribute__((ext_vector_type(8)));
typedef short bf16x4 __attribute__((ext_vector_type(4)));
typedef float f32x4 __attribute__((ext_vector_type(4)));

static __device__ __forceinline__ float b2f(short s) {
    unsigned u = ((unsigned)(unsigned short)s) << 16;
    return __builtin_bit_cast(float, u);
}
static __device__ __forceinline__ short f2b(float f) {   // RNE f32->bf16
    unsigned u = __builtin_bit_cast(unsigned, f);
    u += 0x7fffu + ((u >> 16) & 1u);
    return (short)(u >> 16);
}
static __device__ __forceinline__ void async16(const void* g, void* l) {
    __builtin_amdgcn_global_load_lds(
        (const __attribute__((address_space(1))) unsigned int*)g,
        (__attribute__((address_space(3))) unsigned int*)l, 16, 0, 0);
}

// ---- prep2: W1/W2 convert (vectorized) + k'/v' projections ----
// bid 0..63: convert (8 elems/thread). 64..319: k' (swizzled [b][m][c] bf16).
// 320..575: v' (plain [b][m][c] bf16).
__global__ __launch_bounds__(256) void prep2(
        const float* __restrict__ key, const float* __restrict__ Wk,
        const float* __restrict__ Wv, const float* __restrict__ bv,
        const float* __restrict__ W1, const float* __restrict__ W2,
        short* __restrict__ W1b, short* __restrict__ W2b,
        short* __restrict__ kpb, short* __restrict__ vpb) {
    __shared__ float arow[32][Cn];
    const int bid = blockIdx.x;
    const int t = threadIdx.x;
    if (bid < 64) {                        // convert W1/W2 to bf16, 8/thread
        const int half = bid >> 5;
        const int off = (bid & 31) * 2048 + t * 8;
        const float* src = half ? W2 : W1;
        short* dst = half ? W2b : W1b;
        const float4 a = *(const float4*)(src + off);
        const float4 c = *(const float4*)(src + off + 4);
        bf16x8 p;
        p[0] = f2b(a.x); p[1] = f2b(a.y); p[2] = f2b(a.z); p[3] = f2b(a.w);
        p[4] = f2b(c.x); p[5] = f2b(c.y); p[6] = f2b(c.z); p[7] = f2b(c.w);
        *(bf16x8*)(dst + off) = p;
        return;
    }
    const int isv = bid >= 320;
    const int id = bid - (isv ? 320 : 64);
    const int r0 = (id >> 3) * 32, c0 = (id & 7) * 32;
    const float* W = isv ? Wv : Wk;
    #pragma unroll
    for (int i = 0; i < 32; ++i) arow[i][t] = key[(size_t)(r0 + i) * Cn + t];
    __syncthreads();
    const int col = c0 + (t & 31);
    const int rs = t >> 5;                 // 8 slots x 4 rows
    float a4[4] = {0.f, 0.f, 0.f, 0.f};
    const float* wr = W + (size_t)col * Cn;
    for (int k = 0; k < Cn; k += 4) {
        const float4 wv = *(const float4*)(wr + k);
        #pragma unroll
        for (int i = 0; i < 4; ++i) {
            const int r = rs * 4 + i;
            a4[i] += arow[r][k] * wv.x + arow[r][k+1] * wv.y
                   + arow[r][k+2] * wv.z + arow[r][k+3] * wv.w;
        }
    }
    if (!isv) {                            // k': swizzled rows (async16+ds_read pair)
        const int bk = r0 >> 9, mm0 = (r0 & 511) + rs * 4;
        char* base = (char*)kpb + (size_t)bk * Mn * Cn * 2;
        #pragma unroll
        for (int i = 0; i < 4; ++i) {
            const int m = mm0 + i;
            *(short*)(base + m * 512 + ((col * 2) ^ ((m & 7) << 4))) = f2b(a4[i]);
        }
    } else {                               // v': plain [m][c]
        const float bvv = bv[col];
        #pragma unroll
        for (int i = 0; i < 4; ++i)
            vpb[(size_t)(r0 + rs * 4 + i) * Cn + col] = f2b(a4[i] + bvv);
    }
}

// ---- fused: q'-proj + MLP + gated scores + softmax + PV + out-proj ----
// 512 threads = 8 waves; wave w owns channel slice [w*32,w*32+32) == head w.
// LDS ~72.6 KB -> 2 BLOCKS/CU (independent, not barrier-synced -> true
// MFMA/VALU phase overlap across blocks). Compiler budget: 4 waves/SIMD
// -> 128 VGPRs (R10-proven spill-free working set).
__global__ __launch_bounds__(512) void fused_attn(
        const float* __restrict__ query, const float* __restrict__ Wq,
        const float* __restrict__ bq, const short* __restrict__ kpb,
        const short* __restrict__ vpb, const float* __restrict__ qpos,
        const short* __restrict__ W1b, const short* __restrict__ W2b,
        const float* __restrict__ b1, const float* __restrict__ b2,
        const float* __restrict__ freqs, const float* __restrict__ Wo,
        const float* __restrict__ bo, float* __restrict__ xout) {
    __shared__ __align__(16) char embS[MT * 512];   // 32 KB emb/S, XOR-swizzled
    __shared__ __align__(16) char kS[MT * 512];     // 32 KB K tile [m][c] swz
    __shared__ float tposS[Mn];                     // 2 KB qpos row
    __shared__ float fbuf[128];                     // freqs / 2pi
    __shared__ float qbuf[Cn];                      // q' row, pre-scaled
    __shared__ float b2buf[Cn];
    __shared__ float scb2[Hn * MT];                 // scores -> weights -> x
    __shared__ float pacc[512];
    __shared__ float corrS[Hn], lS[Hn];
    // total ~72.6 KB

    const int t = threadIdx.x;
    const int lane = t & 63;
    const int w = t >> 6;                 // wave id = head id = col-slice id
    const int lr = lane & 15, lg = lane >> 4;

    // XCD-chunked bijective swizzle: 512 blocks = 8 XCDs x 64 contiguous
    const int qrow = ((blockIdx.x & 7) << 6) | (blockIdx.x >> 3);
    const int b = qrow >> 8;              // batch

    const int cA = w * 32 + lr, cB = cA + 16;
    const short* w1p0 = W1b + (size_t)cA * Cn + lg * 8;
    const short* w1p1 = W1b + (size_t)cB * Cn + lg * 8;
    const short* w2p0 = W2b + (size_t)cA * Cn + lg * 8;
    const short* w2p1 = W2b + (size_t)cB * Cn + lg * 8;
    const float b1v0 = b1[cA], b1v1 = b1[cB];

    auto stage_k = [&](int m0w) {
        const size_t tbase = ((size_t)(b * Mn + (m0w & (Mn - 1)))) * Cn * 2;
        #pragma unroll
        for (int i = 0; i < 4; ++i) {
            const int seg = (i * 8 + w) * 1024;
            async16((const char*)kpb + tbase + seg + lane * 16, kS + seg);
        }
    };

    // ---- prologue: constants + q' GEMV + K[0] ----
    tposS[t] = qpos[(size_t)qrow * Mn + t];
    if (t < 128) fbuf[t] = freqs[t] * INV2PI;
    if (t < 256) {
        b2buf[t] = b2[t];
        scb2[t] = query[(size_t)qrow * Cn + t];   // temp stage of query row
    }
    stage_k(0);
    __syncthreads();
    {
        const int c = t & 255, half = t >> 8;
        const float* wr = Wq + (size_t)c * Cn + half * 128;
        const float* xb = scb2 + half * 128;
        float s = 0.f;
        for (int k = 0; k < 128; k += 4) {
            const float4 wv = *(const float4*)(wr + k);
            s += xb[k] * wv.x + xb[k+1] * wv.y + xb[k+2] * wv.z + xb[k+3] * wv.w;
        }
        pacc[t] = s;
    }
    __syncthreads();
    if (t < 256) qbuf[t] = (pacc[t] + pacc[t + 256] + bq[t]) * SCALE_;

    float m_run = -1e30f, l_run = 0.f;
    float xacc = 0.f;                     // t<256: output channel t
    bf16x8 wreg[16];                      // time-shared W fragment buffer
    // preload W1 for tile 0
    #pragma unroll
    for (int kk = 0; kk < 8; ++kk) {
        wreg[kk] = *(const bf16x8*)(w1p0 + kk * 32);
        wreg[8 + kk] = *(const bf16x8*)(w1p1 + kk * 32);
    }

    for (int tix = 0; tix < Mn / MT; ++tix) {
        const int m0 = tix * MT;

        // phase 1: embeddings -> embS. thread: m = t>>3, fg = t&7 (16 freqs)
        {
            const int m = t >> 3, fg = t & 7;
            const float tv = tposS[m0 + m];
            char* rowp = embS + m * 512;
            const int sw = (m & 7) << 4;
            #pragma unroll
            for (int j8 = 0; j8 < 2; ++j8) {
                bf16x8 pc, ps;
                #pragma unroll
                for (int e = 0; e < 8; ++e) {
                    const float xr = tv * fbuf[fg * 16 + j8 * 8 + e];
                    pc[e] = f2b(__builtin_amdgcn_cosf(xr));
                    ps[e] = f2b(__builtin_amdgcn_sinf(xr));
                }
                *(bf16x8*)(rowp + ((fg * 32 + j8 * 16) ^ sw)) = pc;        // cos
                *(bf16x8*)(rowp + ((256 + fg * 32 + j8 * 16) ^ sw)) = ps;  // sin
            }
        }
        __syncthreads();                  // (A) emb + K[t] visible (vmcnt drained)
        // deferred accumulate of previous tile's PV partials
        if (tix > 0 && t < 256) xacc = xacc * corrS[t >> 5] + pacc[t] + pacc[t + 256];

        // phase 2: GEMM1  hidden = emb @ W1^T  (wreg preloaded with W1)
        f32x4 acc[4][2];
        #pragma unroll
        for (int pb = 0; pb < 4; ++pb) {
            acc[pb][0] = (f32x4){0.f, 0.f, 0.f, 0.f};
            acc[pb][1] = (f32x4){0.f, 0.f, 0.f, 0.f};
        }
        #pragma unroll
        for (int pb = 0; pb < 4; ++pb) {
            const int row = pb * 16 + lr;
            const int sw = (row & 7) << 4;
            const char* rowp = embS + row * 512;
            #pragma unroll
            for (int kk = 0; kk < 8; ++kk) {
                const bf16x8 a = *(const bf16x8*)(rowp + ((lg * 16 + kk * 64) ^ sw));
                acc[pb][0] = __builtin_amdgcn_mfma_f32_16x16x32_bf16(a, wreg[kk],     acc[pb][0], 0, 0, 0);
                acc[pb][1] = __builtin_amdgcn_mfma_f32_16x16x32_bf16(a, wreg[8 + kk], acc[pb][1], 0, 0, 0);
            }
        }
        __syncthreads();                  // (B) GEMM1 A-reads done; embS writable

        // wreg <- W2 (opacified; drains under silu)
        {
            int woff = 0;
            asm volatile("" : "+v"(woff));
            #pragma unroll
            for (int kk = 0; kk < 8; ++kk) {
                wreg[kk] = *(const bf16x8*)(w2p0 + woff + kk * 32);
                wreg[8 + kk] = *(const bf16x8*)(w2p1 + woff + kk * 32);
            }
        }
        // silu: hv * rcp(1 + e^-hv)  (v_rcp_f32 instead of full-precision div)
        #pragma unroll
        for (int pb = 0; pb < 4; ++pb) {
            #pragma unroll
            for (int jb = 0; jb < 2; ++jb) {
                const float bv = jb ? b1v1 : b1v0;
                const int j = w * 32 + jb * 16 + lr;
                #pragma unroll
                for (int r = 0; r < 4; ++r) {
                    const int row = pb * 16 + lg * 4 + r;   // C/D: row = 4*(lane>>4)+reg
                    const float hv = acc[pb][jb][r] + bv;
                    const float sg = __builtin_amdgcn_rcpf(1.f + __expf(-hv));
                    *(short*)(embS + row * 512 + ((j * 2) ^ ((row & 7) << 4))) = f2b(hv * sg);
                }
            }
        }
        __syncthreads();                  // (C) S visible

        // phase 3: SWAPPED GEMM2  D2 = W2slice @ S^T  (+b2 via acc init)
        // lane (lr,lg) reg r of acc[mb][cb]: D2[c=w*32+cb*16+lg*4+r][m=mb*16+lr]
        {
            float b2a[8];
            #pragma unroll
            for (int i = 0; i < 8; ++i)
                b2a[i] = b2buf[w * 32 + (i >> 2) * 16 + lg * 4 + (i & 3)];
            #pragma unroll
            for (int mb = 0; mb < 4; ++mb)
                #pragma unroll
                for (int cb = 0; cb < 2; ++cb)
                    #pragma unroll
                    for (int r = 0; r < 4; ++r)
                        acc[mb][cb][r] = b2a[cb * 4 + r];
        }
        #pragma unroll
        for (int mb = 0; mb < 4; ++mb) {
            const int row = mb * 16 + lr;
            const int sw = (row & 7) << 4;
            const char* rowp = embS + row * 512;
            #pragma unroll
            for (int kk = 0; kk < 8; ++kk) {
                const bf16x8 a = *(const bf16x8*)(rowp + ((lg * 16 + kk * 64) ^ sw));
                acc[mb][0] = __builtin_amdgcn_mfma_f32_16x16x32_bf16(wreg[kk],     a, acc[mb][0], 0, 0, 0);
                acc[mb][1] = __builtin_amdgcn_mfma_f32_16x16x32_bf16(wreg[8 + kk], a, acc[mb][1], 0, 0, 0);
            }
        }
        // wreg <- W1 for next tile (opacified; drains under phases 4-6)
        {
            int woff = 0;
            asm volatile("" : "+v"(woff));
            #pragma unroll
            for (int kk = 0; kk < 8; ++kk) {
                wreg[kk] = *(const bf16x8*)(w1p0 + woff + kk * 32);
                wreg[8 + kk] = *(const bf16x8*)(w1p1 + woff + kk * 32);
            }
        }

        // phase 4: s[m] = sum_c q[c]*k[m][c]*D2[c][m]; K from kS; 2-shuffle reduce
        {
            float qa[8];
            #pragma unroll
            for (int i = 0; i < 8; ++i)
                qa[i] = qbuf[w * 32 + (i >> 2) * 16 + lg * 4 + (i & 3)];
            #pragma unroll
            for (int mb = 0; mb < 4; ++mb) {
                const int m = mb * 16 + lr;
                const int sw = (m & 7) << 4;
                const char* kr = kS + m * 512;
                const int cc0 = (w * 32 + lg * 4) * 2;
                const bf16x4 k0 = *(const bf16x4*)(kr + (cc0 ^ sw));
                const bf16x4 k1 = *(const bf16x4*)(kr + ((cc0 + 32) ^ sw));
                float partial = 0.f;
                #pragma unroll
                for (int r = 0; r < 4; ++r) {
                    partial += qa[r] * b2f(k0[r]) * acc[mb][0][r]
                             + qa[4 + r] * b2f(k1[r]) * acc[mb][1][r];
                }
                partial += __shfl_xor(partial, 16);
                partial += __shfl_xor(partial, 32);
                if (lg == 0) scb2[w * MT + m] = partial;
            }
        }

        // phase 5: wave-local online softmax for head w
        {
            const float s = scb2[w * MT + lane];
            float tmax = s;
            #pragma unroll
            for (int msk = 1; msk < 64; msk <<= 1) tmax = fmaxf(tmax, __shfl_xor(tmax, msk));
            const float mnew = fmaxf(m_run, tmax);
            const float corr = __expf(m_run - mnew);
            const float e = __expf(s - mnew);
            scb2[w * MT + lane] = e;
            float ss = e;
            #pragma unroll
            for (int msk = 1; msk < 64; msk <<= 1) ss += __shfl_xor(ss, msk);
            l_run = l_run * corr + ss;
            m_run = mnew;
            if (lane == 0) corrS[w] = corr;
        }
        __syncthreads();                  // (D) weights + corrS visible; kS reads done

        stage_k(m0 + MT);                 // K[t+1] issue; drains under PV + next emb

        // phase 6: PV partials; V direct from L2 (coalesced over c).
        // thread: c = t&255, m-half = t>>8 (32 m each)
        {
            const int c = t & 255, half = t >> 8;
            const int h = c >> 5;
            const short* vrow = vpb + ((size_t)(b * Mn + m0 + half * 32)) * Cn + c;
            const float* wr2 = scb2 + h * MT + half * 32;
            float s = 0.f;
            #pragma unroll
            for (int i = 0; i < 8; ++i) {
                const float4 wa = *(const float4*)(wr2 + i * 4);
                s += wa.x * b2f(vrow[(size_t)(i * 4 + 0) * Cn])
                   + wa.y * b2f(vrow[(size_t)(i * 4 + 1) * Cn])
                   + wa.z * b2f(vrow[(size_t)(i * 4 + 2) * Cn])
                   + wa.w * b2f(vrow[(size_t)(i * 4 + 3) * Cn]);
            }
            pacc[t] = s;
        }
        // no barrier: next iteration's (A) publishes pacc before the deferred use
    }
    __syncthreads();                      // final pacc visible
    if (t < 256) xacc = xacc * corrS[t >> 5] + pacc[t] + pacc[t + 256];

    // epilogue: softmax norm, fused out-projection + bias + residual
    if (lane == 0) lS[w] = l_run;
    __syncthreads();
    if (t < 256) scb2[t] = xacc / lS[t >> 5];    // x vector (256 f32)
    __syncthreads();
    {
        const int j = t & 255, half = t >> 8;
        const float* wr = Wo + (size_t)j * Cn + half * 128;
        const float* xb = scb2 + half * 128;
        float s = 0.f;
        for (int k = 0; k < 128; k += 4) {
            const float4 wv = *(const float4*)(wr + k);
            s += xb[k] * wv.x + xb[k+1] * wv.y + xb[k+2] * wv.z + xb[k+3] * wv.w;
        }
        pacc[t] = s;
    }
    __syncthreads();
    if (t < 256)
        xout[(size_t)qrow * Cn + t] = pacc[t] + pacc[t + 256] + bo[t]
                                    + query[(size_t)qrow * Cn + t];
}

extern "C" void kernel_launch(void* const* d_in, const int* in_sizes, int n_in,
                              void* d_out, int out_size, void* d_ws, size_t ws_size,
                              hipStream_t stream) {
    const float* query = (const float*)d_in[0];
    const float* key   = (const float*)d_in[1];
    const float* qpos  = (const float*)d_in[2];
    const float* Wq    = (const float*)d_in[3];
    const float* bq    = (const float*)d_in[4];
    const float* Wk    = (const float*)d_in[5];
    const float* Wv    = (const float*)d_in[6];
    const float* bv    = (const float*)d_in[7];
    const float* Wo    = (const float*)d_in[8];
    const float* bo    = (const float*)d_in[9];
    const float* W1    = (const float*)d_in[10];
    const float* b1    = (const float*)d_in[11];
    const float* W2    = (const float*)d_in[12];
    const float* b2    = (const float*)d_in[13];
    const float* freqs = (const float*)d_in[14];
    float* out = (float*)d_out;

    char* ws = (char*)d_ws;
    short* kpb = (short*)(ws);                 // 512 KB  (B*M*C bf16, row-swizzled)
    short* vpb = (short*)(ws + 524288);        // 512 KB  (B*M*C bf16, plain)
    short* W1b = (short*)(ws + 1048576);       // 128 KB bf16
    short* W2b = (short*)(ws + 1179648);       // 128 KB bf16

    prep2<<<576, 256, 0, stream>>>(key, Wk, Wv, bv, W1, W2, W1b, W2b, kpb, vpb);
    fused_attn<<<Bn * Nn, 512, 0, stream>>>(query, Wq, bq, kpb, vpb, qpos,
                                            W1b, W2b, b1, b2, freqs, Wo, bo, out);
}